// Round 1
// baseline (1918.638 us; speedup 1.0000x reference)
//
#include <hip/hip_runtime.h>
#include <math.h>

#define T_ 4096
#define NE_ 2048
#define DA_ 2048
#define TDA (T_ * DA_)

constexpr int BM = 128, BN = 128, BK = 8;
constexpr int NC = 64;        // time chunks for the WKV scan
constexpr int CL = T_ / NC;   // 64 steps per chunk

// ---------------------------------------------------------------------------
// Fused (optional time-mix) fp32 GEMM:  O = mix(X) @ W
// mix(X)[t][e] = xx + tm[e]*(x[t][e]-xx), xx = x[t-1][e] (0 for t==0)
// ---------------------------------------------------------------------------
__global__ __launch_bounds__(256) void gemm_mix_kernel(
    const float* __restrict__ X, const float* __restrict__ TM,
    const float* __restrict__ W, float* __restrict__ O,
    int M, int K, int N, int do_mix)
{
  __shared__ float As[BK][BM];   // A stored transposed: As[k][m]
  __shared__ float Bs[BK][BN];

  const int tid = threadIdx.x;
  const int bm = blockIdx.x * BM;
  const int bn = blockIdx.y * BN;

  // A-tile load mapping: 128x8 tile, each thread one float4
  const int ar = tid >> 1;            // row in tile 0..127
  const int ac = (tid & 1) * 4;       // k-col 0 or 4
  // B-tile load mapping: 8x128 tile, each thread one float4
  const int br = tid >> 5;            // 0..7
  const int bc = (tid & 31) * 4;      // 0..124
  // compute mapping: 16x16 threads, 8x8 outputs each
  const int ty = tid >> 4;
  const int tx = tid & 15;

  float acc[8][8];
#pragma unroll
  for (int i = 0; i < 8; ++i)
#pragma unroll
    for (int j = 0; j < 8; ++j) acc[i][j] = 0.f;

  const int arow = bm + ar;

  auto loadA = [&](int kk) -> float4 {
    float4 xv = *reinterpret_cast<const float4*>(&X[(size_t)arow * K + kk + ac]);
    if (do_mix) {
      float4 xp = make_float4(0.f, 0.f, 0.f, 0.f);
      if (arow > 0)
        xp = *reinterpret_cast<const float4*>(&X[(size_t)(arow - 1) * K + kk + ac]);
      float4 tm = *reinterpret_cast<const float4*>(&TM[kk + ac]);
      xv.x = xp.x + tm.x * (xv.x - xp.x);
      xv.y = xp.y + tm.y * (xv.y - xp.y);
      xv.z = xp.z + tm.z * (xv.z - xp.z);
      xv.w = xp.w + tm.w * (xv.w - xp.w);
    }
    return xv;
  };
  auto loadB = [&](int kk) -> float4 {
    return *reinterpret_cast<const float4*>(&W[(size_t)(kk + br) * N + bn + bc]);
  };

  float4 aReg = loadA(0);
  float4 bReg = loadB(0);

  for (int kk = 0; kk < K; kk += BK) {
    __syncthreads();
    As[ac + 0][ar] = aReg.x;
    As[ac + 1][ar] = aReg.y;
    As[ac + 2][ar] = aReg.z;
    As[ac + 3][ar] = aReg.w;
    *reinterpret_cast<float4*>(&Bs[br][bc]) = bReg;
    __syncthreads();
    if (kk + BK < K) { aReg = loadA(kk + BK); bReg = loadB(kk + BK); }
#pragma unroll
    for (int k = 0; k < BK; ++k) {
      float4 a0 = *reinterpret_cast<const float4*>(&As[k][ty * 8]);
      float4 a1 = *reinterpret_cast<const float4*>(&As[k][ty * 8 + 4]);
      float4 b0 = *reinterpret_cast<const float4*>(&Bs[k][tx * 8]);
      float4 b1 = *reinterpret_cast<const float4*>(&Bs[k][tx * 8 + 4]);
      float a[8] = {a0.x, a0.y, a0.z, a0.w, a1.x, a1.y, a1.z, a1.w};
      float b[8] = {b0.x, b0.y, b0.z, b0.w, b1.x, b1.y, b1.z, b1.w};
#pragma unroll
      for (int i = 0; i < 8; ++i)
#pragma unroll
        for (int j = 0; j < 8; ++j)
          acc[i][j] = fmaf(a[i], b[j], acc[i][j]);
    }
  }

#pragma unroll
  for (int i = 0; i < 8; ++i) {
    const size_t row = (size_t)(bm + ty * 8 + i) * N + bn + tx * 8;
    float4 o0 = make_float4(acc[i][0], acc[i][1], acc[i][2], acc[i][3]);
    float4 o1 = make_float4(acc[i][4], acc[i][5], acc[i][6], acc[i][7]);
    *reinterpret_cast<float4*>(&O[row]) = o0;
    *reinterpret_cast<float4*>(&O[row + 4]) = o1;
  }
}

// ---------------------------------------------------------------------------
// WKV chunked linear scan. Unnormalized recurrence (fp32-safe):
//   P_t = lam*P_{t-1} + e^{k_t} v_t ,  Q_t = lam*Q_{t-1} + e^{k_t}
//   y_t = (P_{t-1} + e^{u+k_t} v_t) / (Q_{t-1} + e^{u+k_t})
// lam = exp(-exp(time_decay[c])) per channel.
// ---------------------------------------------------------------------------
__global__ __launch_bounds__(256) void wkv_pass1(
    const float* __restrict__ Kb, const float* __restrict__ Vb,
    const float* __restrict__ td, float* __restrict__ SP, float* __restrict__ SQ)
{
  const int c = blockIdx.x * 256 + threadIdx.x;
  const int chunk = blockIdx.y;
  const int t0 = chunk * CL;
  const float lam = __expf(-__expf(td[c]));
  float P = 0.f, Q = 0.f;
  for (int t = t0; t < t0 + CL; ++t) {
    const float kt = Kb[(size_t)t * DA_ + c];
    const float vt = Vb[(size_t)t * DA_ + c];
    const float e = __expf(kt);
    P = fmaf(lam, P, e * vt);
    Q = fmaf(lam, Q, e);
  }
  SP[(size_t)chunk * DA_ + c] = P;
  SQ[(size_t)chunk * DA_ + c] = Q;
}

__global__ __launch_bounds__(256) void wkv_pass2(
    const float* __restrict__ td, float* __restrict__ SP, float* __restrict__ SQ)
{
  const int c = blockIdx.x * 256 + threadIdx.x;
  const float lamL = __expf(-__expf(td[c]) * (float)CL);  // lam^CL
  float P = 0.f, Q = 0.f;
  for (int i = 0; i < NC; ++i) {
    const float sp = SP[(size_t)i * DA_ + c];
    const float sq = SQ[(size_t)i * DA_ + c];
    SP[(size_t)i * DA_ + c] = P;   // exclusive prefix (state before this chunk)
    SQ[(size_t)i * DA_ + c] = Q;
    P = fmaf(lamL, P, sp);
    Q = fmaf(lamL, Q, sq);
  }
}

__global__ __launch_bounds__(256) void wkv_pass3(
    const float* __restrict__ Kb, const float* __restrict__ Vb,
    float* __restrict__ Rb,  // in: r; out: sigmoid(r)*wkv (in place)
    const float* __restrict__ td, const float* __restrict__ tf,
    const float* __restrict__ SP, const float* __restrict__ SQ)
{
  const int c = blockIdx.x * 256 + threadIdx.x;
  const int chunk = blockIdx.y;
  const int t0 = chunk * CL;
  const float lam = __expf(-__expf(td[c]));
  const float eu = __expf(tf[c]);
  float P = SP[(size_t)chunk * DA_ + c];
  float Q = SQ[(size_t)chunk * DA_ + c];
  for (int t = t0; t < t0 + CL; ++t) {
    const size_t idx = (size_t)t * DA_ + c;
    const float kt = Kb[idx];
    const float vt = Vb[idx];
    const float rt = Rb[idx];
    const float e = __expf(kt);
    const float b = eu * e;
    const float y = (P + b * vt) / (Q + b);
    const float sr = 1.f / (1.f + __expf(-rt));
    Rb[idx] = sr * y;
    P = fmaf(lam, P, e * vt);
    Q = fmaf(lam, Q, e);
  }
}

// ---------------------------------------------------------------------------
extern "C" void kernel_launch(void* const* d_in, const int* in_sizes, int n_in,
                              void* d_out, int out_size, void* d_ws, size_t ws_size,
                              hipStream_t stream)
{
  const float* x   = (const float*)d_in[0];
  const float* tf  = (const float*)d_in[1];  // time_first   [DA]
  const float* td  = (const float*)d_in[2];  // time_decay   [DA]
  const float* tmk = (const float*)d_in[3];
  const float* tmv = (const float*)d_in[4];
  const float* tmr = (const float*)d_in[5];
  const float* Wk  = (const float*)d_in[6];  // [NE, DA]
  const float* Wv  = (const float*)d_in[7];
  const float* Wr  = (const float*)d_in[8];
  const float* Wo  = (const float*)d_in[9];  // [DA, NE]
  float* out = (float*)d_out;

  float* kb = (float*)d_ws;          // [T, DA]
  float* vb = kb + (size_t)TDA;      // [T, DA]
  float* rb = vb + (size_t)TDA;      // [T, DA]; becomes sr*wkv in place
  float* sp = rb + (size_t)TDA;      // [NC, DA]
  float* sq = sp + (size_t)NC * DA_; // [NC, DA]

  dim3 blk(256);
  dim3 gemm_grid(T_ / BM, DA_ / BN);  // 32 x 16

  // k, v, r projections with fused time-mix
  gemm_mix_kernel<<<gemm_grid, blk, 0, stream>>>(x, tmk, Wk, kb, T_, NE_, DA_, 1);
  gemm_mix_kernel<<<gemm_grid, blk, 0, stream>>>(x, tmv, Wv, vb, T_, NE_, DA_, 1);
  gemm_mix_kernel<<<gemm_grid, blk, 0, stream>>>(x, tmr, Wr, rb, T_, NE_, DA_, 1);

  // WKV chunked scan + fused sigmoid(r) multiply (in place into rb)
  wkv_pass1<<<dim3(DA_ / 256, NC), blk, 0, stream>>>(kb, vb, td, sp, sq);
  wkv_pass2<<<dim3(DA_ / 256), blk, 0, stream>>>(td, sp, sq);
  wkv_pass3<<<dim3(DA_ / 256, NC), blk, 0, stream>>>(kb, vb, rb, td, tf, sp, sq);

  // output projection: (sr*wkv) @ W_output
  gemm_mix_kernel<<<dim3(T_ / BM, NE_ / BN), blk, 0, stream>>>(
      rb, nullptr, Wo, out, T_, DA_, NE_, 0);
}

// Round 2
// 440.347 us; speedup vs baseline: 4.3571x; 4.3571x over previous
//
#include <hip/hip_runtime.h>
#include <math.h>

#define T_ 4096
#define NE_ 2048
#define DA_ 2048
#define TDA (T_ * NE_)

constexpr int NC = 64;        // time chunks for the WKV scan
constexpr int CL = T_ / NC;   // 64 steps per chunk

typedef __attribute__((ext_vector_type(8))) short short8;
typedef __attribute__((ext_vector_type(4))) float f32x4;

__device__ __forceinline__ unsigned short f2bf(float f) {
  union { float f; unsigned int u; } v; v.f = f;
  unsigned int u = v.u;
  return (unsigned short)((u + 0x7FFFu + ((u >> 16) & 1u)) >> 16);  // RNE
}
__device__ __forceinline__ float bf2f(unsigned short h) {
  union { unsigned int u; float f; } v; v.u = ((unsigned int)h) << 16;
  return v.f;
}

__device__ __forceinline__ void gload_lds16(const void* g, void* l) {
  __builtin_amdgcn_global_load_lds(
      (const __attribute__((address_space(1))) void*)g,
      (__attribute__((address_space(3))) void*)l, 16, 0, 0);
}

// ---------------------------------------------------------------------------
// bf16 MFMA GEMM (m97 structure): C[M][N] = A[M][K] * Bt[N][K]^T
// 128x128 tile, BK=32, 4 waves (2x2), each wave 64x64 = 4x4 x (16x16x32 MFMA).
// Staging via global_load_lds width=16 (linear LDS [128][32] bf16).
// c_bf16: 0 -> fp32 C, 1 -> bf16 C.
// ---------------------------------------------------------------------------
__global__ __launch_bounds__(256) void gemm_bf16(
    const unsigned short* __restrict__ A,   // [M][K] bf16
    const unsigned short* __restrict__ Bt,  // [N][K] bf16
    void* __restrict__ C, int M, int N, int K, int c_bf16)
{
  __shared__ unsigned short As[128 * 32];
  __shared__ unsigned short Bs[128 * 32];

  const int tid = threadIdx.x;
  const int w = tid >> 6, lane = tid & 63;
  const int bm = blockIdx.x * 128, bn = blockIdx.y * 128;
  const int wr = w >> 1, wc = w & 1;

  f32x4 acc[4][4];
#pragma unroll
  for (int m = 0; m < 4; ++m)
#pragma unroll
    for (int n = 0; n < 4; ++n) acc[m][n] = (f32x4){0.f, 0.f, 0.f, 0.f};

  // staging: wave w covers tile rows [w*32, w*32+32), 2 loads of 16 rows
  const int srow = w * 32 + (lane >> 2);   // row within tile
  const int scol = (lane & 3) * 8;         // elem col within 32 (16B per lane)
  const size_t gA0 = (size_t)(bm + srow) * K + scol;
  const size_t gB0 = (size_t)(bn + srow) * K + scol;
  unsigned short* lA = &As[w * 1024];      // wave-uniform LDS base (HW adds lane*16B)
  unsigned short* lB = &Bs[w * 1024];

  const int lr = lane & 15, lk = (lane >> 4) * 8;
  const int arow = wr * 64 + lr;
  const int brow = wc * 64 + lr;

  for (int kk = 0; kk < K; kk += 32) {
    __syncthreads();                        // previous tile consumed
    gload_lds16(A + gA0 + kk, lA);
    gload_lds16(A + gA0 + kk + (size_t)16 * K, lA + 512);
    gload_lds16(Bt + gB0 + kk, lB);
    gload_lds16(Bt + gB0 + kk + (size_t)16 * K, lB + 512);
    __syncthreads();                        // drains vmcnt -> LDS ready

    short8 af[4], bfr[4];
#pragma unroll
    for (int m = 0; m < 4; ++m)
      af[m] = *reinterpret_cast<const short8*>(&As[(arow + m * 16) * 32 + lk]);
#pragma unroll
    for (int n = 0; n < 4; ++n)
      bfr[n] = *reinterpret_cast<const short8*>(&Bs[(brow + n * 16) * 32 + lk]);
#pragma unroll
    for (int m = 0; m < 4; ++m)
#pragma unroll
      for (int n = 0; n < 4; ++n)
        acc[m][n] = __builtin_amdgcn_mfma_f32_16x16x32_bf16(af[m], bfr[n], acc[m][n], 0, 0, 0);
  }

  // C/D layout (verified m89/m91): col = lane&15, row = (lane>>4)*4 + reg
  const int crow0 = bm + wr * 64 + (lane >> 4) * 4;
  const int ccol0 = bn + wc * 64 + (lane & 15);
  if (c_bf16) {
    unsigned short* Cb = (unsigned short*)C;
#pragma unroll
    for (int m = 0; m < 4; ++m)
#pragma unroll
      for (int n = 0; n < 4; ++n)
#pragma unroll
        for (int j = 0; j < 4; ++j)
          Cb[(size_t)(crow0 + m * 16 + j) * N + ccol0 + n * 16] = f2bf(acc[m][n][j]);
  } else {
    float* Cf = (float*)C;
#pragma unroll
    for (int m = 0; m < 4; ++m)
#pragma unroll
      for (int n = 0; n < 4; ++n)
#pragma unroll
        for (int j = 0; j < 4; ++j)
          Cf[(size_t)(crow0 + m * 16 + j) * N + ccol0 + n * 16] = acc[m][n][j];
  }
}

// ---------------------------------------------------------------------------
// time-mix + fp32->bf16: o[t][e] = bf16( xx + tm[e]*(x[t][e]-xx) ), xx=x[t-1][e]
// ---------------------------------------------------------------------------
__global__ __launch_bounds__(256) void mix_cvt(
    const float* __restrict__ x, const float* __restrict__ tm,
    unsigned short* __restrict__ o)
{
  const int i = blockIdx.x * 256 + threadIdx.x;   // float4 index
  const int t = i / (NE_ / 4);
  const int e4 = i % (NE_ / 4);
  const float4 xc = reinterpret_cast<const float4*>(x)[i];
  float4 xp = make_float4(0.f, 0.f, 0.f, 0.f);
  if (t > 0) xp = reinterpret_cast<const float4*>(x)[i - NE_ / 4];
  const float4 m4 = reinterpret_cast<const float4*>(tm)[e4];
  ushort4 r;
  r.x = f2bf(xp.x + m4.x * (xc.x - xp.x));
  r.y = f2bf(xp.y + m4.y * (xc.y - xp.y));
  r.z = f2bf(xp.z + m4.z * (xc.z - xp.z));
  r.w = f2bf(xp.w + m4.w * (xc.w - xp.w));
  reinterpret_cast<ushort4*>(o)[i] = r;
}

// ---------------------------------------------------------------------------
// transpose + fp32->bf16: Wt[n][k] = bf16(W[k][n]);  W is [K][N]
// ---------------------------------------------------------------------------
__global__ __launch_bounds__(256) void transpose_cvt(
    const float* __restrict__ W, unsigned short* __restrict__ Wt, int K, int N)
{
  __shared__ float tile[32][33];
  const int bk = blockIdx.y * 32;
  const int bn = blockIdx.x * 32;
  const int tx = threadIdx.x;   // 0..31
  const int ty = threadIdx.y;   // 0..7
#pragma unroll
  for (int i = 0; i < 32; i += 8)
    tile[ty + i][tx] = W[(size_t)(bk + ty + i) * N + bn + tx];
  __syncthreads();
#pragma unroll
  for (int i = 0; i < 32; i += 8)
    Wt[(size_t)(bn + ty + i) * K + bk + tx] = f2bf(tile[tx][ty + i]);
}

// ---------------------------------------------------------------------------
// WKV chunked linear scan (fp32 k,v; bf16 r in, bf16 a=sigmoid(r)*wkv out)
// ---------------------------------------------------------------------------
__global__ __launch_bounds__(256) void wkv_pass1(
    const float* __restrict__ Kb, const float* __restrict__ Vb,
    const float* __restrict__ td, float* __restrict__ SP, float* __restrict__ SQ)
{
  const int c = blockIdx.x * 256 + threadIdx.x;
  const int chunk = blockIdx.y;
  const int t0 = chunk * CL;
  const float lam = __expf(-__expf(td[c]));
  float P = 0.f, Q = 0.f;
  for (int t = t0; t < t0 + CL; ++t) {
    const float kt = Kb[(size_t)t * DA_ + c];
    const float vt = Vb[(size_t)t * DA_ + c];
    const float e = __expf(kt);
    P = fmaf(lam, P, e * vt);
    Q = fmaf(lam, Q, e);
  }
  SP[(size_t)chunk * DA_ + c] = P;
  SQ[(size_t)chunk * DA_ + c] = Q;
}

__global__ __launch_bounds__(256) void wkv_pass2(
    const float* __restrict__ td, float* __restrict__ SP, float* __restrict__ SQ)
{
  const int c = blockIdx.x * 256 + threadIdx.x;
  const float lamL = __expf(-__expf(td[c]) * (float)CL);  // lam^CL
  float P = 0.f, Q = 0.f;
  for (int i = 0; i < NC; ++i) {
    const float sp = SP[(size_t)i * DA_ + c];
    const float sq = SQ[(size_t)i * DA_ + c];
    SP[(size_t)i * DA_ + c] = P;   // exclusive prefix
    SQ[(size_t)i * DA_ + c] = Q;
    P = fmaf(lamL, P, sp);
    Q = fmaf(lamL, Q, sq);
  }
}

__global__ __launch_bounds__(256) void wkv_pass3(
    const float* __restrict__ Kb, const float* __restrict__ Vb,
    const unsigned short* __restrict__ Rb, unsigned short* __restrict__ Ab,
    const float* __restrict__ td, const float* __restrict__ tf,
    const float* __restrict__ SP, const float* __restrict__ SQ)
{
  const int c = blockIdx.x * 256 + threadIdx.x;
  const int chunk = blockIdx.y;
  const int t0 = chunk * CL;
  const float lam = __expf(-__expf(td[c]));
  const float eu = __expf(tf[c]);
  float P = SP[(size_t)chunk * DA_ + c];
  float Q = SQ[(size_t)chunk * DA_ + c];
  for (int t = t0; t < t0 + CL; ++t) {
    const size_t idx = (size_t)t * DA_ + c;
    const float kt = Kb[idx];
    const float vt = Vb[idx];
    const float rt = bf2f(Rb[idx]);
    const float e = __expf(kt);
    const float b = eu * e;
    const float y = (P + b * vt) / (Q + b);
    const float sr = 1.f / (1.f + __expf(-rt));
    Ab[idx] = f2bf(sr * y);
    P = fmaf(lam, P, e * vt);
    Q = fmaf(lam, Q, e);
  }
}

// ---------------------------------------------------------------------------
extern "C" void kernel_launch(void* const* d_in, const int* in_sizes, int n_in,
                              void* d_out, int out_size, void* d_ws, size_t ws_size,
                              hipStream_t stream)
{
  const float* x   = (const float*)d_in[0];
  const float* tf  = (const float*)d_in[1];
  const float* td  = (const float*)d_in[2];
  const float* tmk = (const float*)d_in[3];
  const float* tmv = (const float*)d_in[4];
  const float* tmr = (const float*)d_in[5];
  const float* Wk  = (const float*)d_in[6];  // [NE, DA]
  const float* Wv  = (const float*)d_in[7];
  const float* Wr  = (const float*)d_in[8];
  const float* Wo  = (const float*)d_in[9];  // [DA, NE]
  float* out = (float*)d_out;

  // workspace layout (bytes), total ~105 MB
  char* ws = (char*)d_ws;
  unsigned short* xmix = (unsigned short*)ws;            // [T,NE] bf16; reused as `a` after pass3
  unsigned short* Wt   = (unsigned short*)(ws + 16777216);  // [2048][2048] bf16, reused 4x
  float* kb = (float*)(ws + 25165824);                   // [T,DA] fp32
  float* vb = (float*)(ws + 58720256);                   // [T,DA] fp32
  unsigned short* rb = (unsigned short*)(ws + 92274688); // [T,DA] bf16
  float* sp = (float*)(ws + 109051904);                  // [NC,DA]
  float* sq = (float*)(ws + 109576192);                  // [NC,DA]

  const dim3 blk(256);
  const dim3 gemm_grid(T_ / 128, DA_ / 128);  // 32 x 16
  const dim3 tgrid(DA_ / 32, NE_ / 32);       // 64 x 64 (all Ws are 2048x2048)
  const dim3 tblk(32, 8);

  // k = mix_k(x) @ Wk
  transpose_cvt<<<tgrid, tblk, 0, stream>>>(Wk, Wt, NE_, DA_);
  mix_cvt<<<TDA / 4 / 256, blk, 0, stream>>>(x, tmk, xmix);
  gemm_bf16<<<gemm_grid, blk, 0, stream>>>(xmix, Wt, kb, T_, DA_, NE_, 0);
  // v = mix_v(x) @ Wv
  transpose_cvt<<<tgrid, tblk, 0, stream>>>(Wv, Wt, NE_, DA_);
  mix_cvt<<<TDA / 4 / 256, blk, 0, stream>>>(x, tmv, xmix);
  gemm_bf16<<<gemm_grid, blk, 0, stream>>>(xmix, Wt, vb, T_, DA_, NE_, 0);
  // r = mix_r(x) @ Wr  (bf16 output)
  transpose_cvt<<<tgrid, tblk, 0, stream>>>(Wr, Wt, NE_, DA_);
  mix_cvt<<<TDA / 4 / 256, blk, 0, stream>>>(x, tmr, xmix);
  gemm_bf16<<<gemm_grid, blk, 0, stream>>>(xmix, Wt, rb, T_, DA_, NE_, 1);

  // WKV chunked scan; pass3 writes a = sigmoid(r)*wkv as bf16 into xmix
  wkv_pass1<<<dim3(DA_ / 256, NC), blk, 0, stream>>>(kb, vb, td, sp, sq);
  wkv_pass2<<<dim3(DA_ / 256), blk, 0, stream>>>(td, sp, sq);
  wkv_pass3<<<dim3(DA_ / 256, NC), blk, 0, stream>>>(kb, vb, rb, xmix, td, tf, sp, sq);

  // out = a @ Wo
  transpose_cvt<<<dim3(NE_ / 32, DA_ / 32), tblk, 0, stream>>>(Wo, Wt, DA_, NE_);
  gemm_bf16<<<dim3(T_ / 128, NE_ / 128), blk, 0, stream>>>(xmix, Wt, out, T_, NE_, DA_, 0);
}

// Round 3
// 421.124 us; speedup vs baseline: 4.5560x; 1.0456x over previous
//
#include <hip/hip_runtime.h>
#include <math.h>

#define T_ 4096
#define NE_ 2048
#define DA_ 2048
#define TDA ((size_t)T_ * NE_)

constexpr int NC = 64;        // time chunks for the WKV scan
constexpr int CL = T_ / NC;   // 64 steps per chunk

typedef __attribute__((ext_vector_type(8))) short short8;
typedef __attribute__((ext_vector_type(4))) float f32x4;

__device__ __forceinline__ unsigned short f2bf(float f) {
  union { float f; unsigned int u; } v; v.f = f;
  unsigned int u = v.u;
  return (unsigned short)((u + 0x7FFFu + ((u >> 16) & 1u)) >> 16);  // RNE
}
__device__ __forceinline__ float bf2f(unsigned short h) {
  union { unsigned int u; float f; } v; v.u = ((unsigned int)h) << 16;
  return v.f;
}

__device__ __forceinline__ void gload_lds16(const void* g, void* l) {
  __builtin_amdgcn_global_load_lds(
      (const __attribute__((address_space(1))) void*)g,
      (__attribute__((address_space(3))) void*)l, 16, 0, 0);
}

// ---------------------------------------------------------------------------
// bf16 MFMA GEMM core (m97 structure + both-sides chunk swizzle):
//   C[4096][2048] = A[4096][2048] * Bt[2048][2048]^T      (all K=2048)
// 128x128 tile, BK=32, 4 waves (2x2), 4x4 x (16x16x32 MFMA) per wave.
// LDS tile [128][32] bf16; row = 64B = 16 banks -> linear reads are 8-way
// conflicted. Swizzle: 16B-chunk c of row r stored at slot c ^ ((r>>1)&3);
// achieved by pre-swizzling the global source chunk (gload_lds dest stays
// linear, rule 21) and XOR-ing the same term into ds_read addresses.
// ---------------------------------------------------------------------------
__device__ __forceinline__ void gemm_core(
    const unsigned short* __restrict__ A, const unsigned short* __restrict__ Bt,
    void* __restrict__ C, int c_bf16)
{
  constexpr int K = 2048, N = 2048;
  __shared__ unsigned short As[128 * 32];
  __shared__ unsigned short Bs[128 * 32];

  const int tid = threadIdx.x;
  const int w = tid >> 6, lane = tid & 63;
  const int bm = blockIdx.x * 128, bn = blockIdx.y * 128;
  const int wr = w >> 1, wc = w & 1;

  f32x4 acc[4][4];
#pragma unroll
  for (int m = 0; m < 4; ++m)
#pragma unroll
    for (int n = 0; n < 4; ++n) acc[m][n] = (f32x4){0.f, 0.f, 0.f, 0.f};

  // staging: wave w covers tile rows [w*32, w*32+32), two 16-row gloads.
  // swizzled source chunk: gc = (lane&3) ^ ((row>>1)&3), row = lane>>2
  // (row+16 has the same swizzle term since 16>>1 = 8 ≡ 0 mod 4).
  const int sr = lane >> 2;
  const int gc = (lane & 3) ^ ((lane >> 3) & 3);
  const size_t gA0 = (size_t)(bm + w * 32 + sr) * K + gc * 8;
  const size_t gB0 = (size_t)(bn + w * 32 + sr) * K + gc * 8;
  unsigned short* lA = &As[w * 1024];      // wave-uniform base, HW adds lane*16B
  unsigned short* lB = &Bs[w * 1024];

  const int lr = lane & 15, ck = lane >> 4;
  const int coff = ((ck ^ ((lr >> 1) & 3)) << 3);  // swizzled elem offset in row
  const int arow = wr * 64 + lr;
  const int brow = wc * 64 + lr;

  for (int kk = 0; kk < K; kk += 32) {
    __syncthreads();                        // previous tile consumed
    gload_lds16(A + gA0 + kk, lA);
    gload_lds16(A + gA0 + kk + (size_t)16 * K, lA + 512);
    gload_lds16(Bt + gB0 + kk, lB);
    gload_lds16(Bt + gB0 + kk + (size_t)16 * K, lB + 512);
    __syncthreads();                        // drains vmcnt -> LDS ready

    short8 af[4], bfr[4];
#pragma unroll
    for (int m = 0; m < 4; ++m)
      af[m] = *reinterpret_cast<const short8*>(&As[(arow + m * 16) * 32 + coff]);
#pragma unroll
    for (int n = 0; n < 4; ++n)
      bfr[n] = *reinterpret_cast<const short8*>(&Bs[(brow + n * 16) * 32 + coff]);
#pragma unroll
    for (int m = 0; m < 4; ++m)
#pragma unroll
      for (int n = 0; n < 4; ++n)
        acc[m][n] = __builtin_amdgcn_mfma_f32_16x16x32_bf16(af[m], bfr[n], acc[m][n], 0, 0, 0);
  }

  // C/D layout (verified m89/m91): col = lane&15, row = (lane>>4)*4 + reg
  const int crow0 = bm + wr * 64 + (lane >> 4) * 4;
  const int ccol0 = bn + wc * 64 + (lane & 15);
  if (c_bf16) {
    unsigned short* Cb = (unsigned short*)C;
#pragma unroll
    for (int m = 0; m < 4; ++m)
#pragma unroll
      for (int n = 0; n < 4; ++n)
#pragma unroll
        for (int j = 0; j < 4; ++j)
          Cb[(size_t)(crow0 + m * 16 + j) * N + ccol0 + n * 16] = f2bf(acc[m][n][j]);
  } else {
    float* Cf = (float*)C;
#pragma unroll
    for (int m = 0; m < 4; ++m)
#pragma unroll
      for (int n = 0; n < 4; ++n)
#pragma unroll
        for (int j = 0; j < 4; ++j)
          Cf[(size_t)(crow0 + m * 16 + j) * N + ccol0 + n * 16] = acc[m][n][j];
  }
}

// z-batched GEMM: blockIdx.z selects (A, Bt, C) triple.
__global__ __launch_bounds__(256) void gemm3_bf16(
    const unsigned short* __restrict__ A0, const unsigned short* __restrict__ A1,
    const unsigned short* __restrict__ A2,
    const unsigned short* __restrict__ B0, const unsigned short* __restrict__ B1,
    const unsigned short* __restrict__ B2,
    void* __restrict__ C0, void* __restrict__ C1, void* __restrict__ C2,
    int c_bf16)
{
  const int z = blockIdx.z;
  const unsigned short* A = (z == 0) ? A0 : (z == 1) ? A1 : A2;
  const unsigned short* B = (z == 0) ? B0 : (z == 1) ? B1 : B2;
  void* C = (z == 0) ? C0 : (z == 1) ? C1 : C2;
  gemm_core(A, B, C, c_bf16);
}

// ---------------------------------------------------------------------------
// z-batched transpose + fp32->bf16 for 2048x2048: O[n][k] = bf16(W[k][n])
// ---------------------------------------------------------------------------
__global__ __launch_bounds__(256) void transpose_cvt3(
    const float* __restrict__ W0, const float* __restrict__ W1,
    const float* __restrict__ W2,
    unsigned short* __restrict__ O0, unsigned short* __restrict__ O1,
    unsigned short* __restrict__ O2)
{
  constexpr int K = 2048, N = 2048;
  const int z = blockIdx.z;
  const float* W = (z == 0) ? W0 : (z == 1) ? W1 : W2;
  unsigned short* O = (z == 0) ? O0 : (z == 1) ? O1 : O2;

  __shared__ float tile[32][33];
  const int bk = blockIdx.y * 32;
  const int bn = blockIdx.x * 32;
  const int tx = threadIdx.x;   // 0..31
  const int ty = threadIdx.y;   // 0..7
#pragma unroll
  for (int i = 0; i < 32; i += 8)
    tile[ty + i][tx] = W[(size_t)(bk + ty + i) * N + bn + tx];
  __syncthreads();
#pragma unroll
  for (int i = 0; i < 32; i += 8)
    O[(size_t)(bn + ty + i) * K + bk + tx] = f2bf(tile[tx][ty + i]);
}

// ---------------------------------------------------------------------------
// Fused triple time-mix + fp32->bf16 (reads x once)
// ---------------------------------------------------------------------------
__global__ __launch_bounds__(256) void mix3_cvt(
    const float* __restrict__ x,
    const float* __restrict__ tmk, const float* __restrict__ tmv,
    const float* __restrict__ tmr,
    unsigned short* __restrict__ ok, unsigned short* __restrict__ ov,
    unsigned short* __restrict__ orr)
{
  const int i = blockIdx.x * 256 + threadIdx.x;   // float4 index
  const int t = i / (NE_ / 4);
  const int e4 = i % (NE_ / 4);
  const float4 xc = reinterpret_cast<const float4*>(x)[i];
  float4 xp = make_float4(0.f, 0.f, 0.f, 0.f);
  if (t > 0) xp = reinterpret_cast<const float4*>(x)[i - NE_ / 4];
  const float4 dx = make_float4(xc.x - xp.x, xc.y - xp.y, xc.z - xp.z, xc.w - xp.w);

  float4 m;
  ushort4 r;
  m = reinterpret_cast<const float4*>(tmk)[e4];
  r.x = f2bf(xp.x + m.x * dx.x); r.y = f2bf(xp.y + m.y * dx.y);
  r.z = f2bf(xp.z + m.z * dx.z); r.w = f2bf(xp.w + m.w * dx.w);
  reinterpret_cast<ushort4*>(ok)[i] = r;
  m = reinterpret_cast<const float4*>(tmv)[e4];
  r.x = f2bf(xp.x + m.x * dx.x); r.y = f2bf(xp.y + m.y * dx.y);
  r.z = f2bf(xp.z + m.z * dx.z); r.w = f2bf(xp.w + m.w * dx.w);
  reinterpret_cast<ushort4*>(ov)[i] = r;
  m = reinterpret_cast<const float4*>(tmr)[e4];
  r.x = f2bf(xp.x + m.x * dx.x); r.y = f2bf(xp.y + m.y * dx.y);
  r.z = f2bf(xp.z + m.z * dx.z); r.w = f2bf(xp.w + m.w * dx.w);
  reinterpret_cast<ushort4*>(orr)[i] = r;
}

// ---------------------------------------------------------------------------
// WKV chunked linear scan, bf16 k/v, 4 channels per thread (ushort4 loads).
//   P_t = lam*P + e^{k_t} v_t ,  Q_t = lam*Q + e^{k_t}
//   y_t = (P_{t-1} + e^{u+k_t} v_t) / (Q_{t-1} + e^{u+k_t})
// ---------------------------------------------------------------------------
__global__ __launch_bounds__(256) void wkv_pass1(
    const unsigned short* __restrict__ Kb, const unsigned short* __restrict__ Vb,
    const float* __restrict__ td, float* __restrict__ SP, float* __restrict__ SQ)
{
  const int c4 = blockIdx.x * 256 + threadIdx.x;   // 4-channel group
  const int chunk = blockIdx.y;
  const int t0 = chunk * CL;
  const float4 tdv = reinterpret_cast<const float4*>(td)[c4];
  float lam[4] = {__expf(-__expf(tdv.x)), __expf(-__expf(tdv.y)),
                  __expf(-__expf(tdv.z)), __expf(-__expf(tdv.w))};
  float P[4] = {0.f, 0.f, 0.f, 0.f}, Q[4] = {0.f, 0.f, 0.f, 0.f};
  for (int t = t0; t < t0 + CL; ++t) {
    const ushort4 kq = reinterpret_cast<const ushort4*>(Kb + (size_t)t * DA_)[c4];
    const ushort4 vq = reinterpret_cast<const ushort4*>(Vb + (size_t)t * DA_)[c4];
    const float kf[4] = {bf2f(kq.x), bf2f(kq.y), bf2f(kq.z), bf2f(kq.w)};
    const float vf[4] = {bf2f(vq.x), bf2f(vq.y), bf2f(vq.z), bf2f(vq.w)};
#pragma unroll
    for (int j = 0; j < 4; ++j) {
      const float e = __expf(kf[j]);
      P[j] = fmaf(lam[j], P[j], e * vf[j]);
      Q[j] = fmaf(lam[j], Q[j], e);
    }
  }
  reinterpret_cast<float4*>(SP + (size_t)chunk * DA_)[c4] = (float4){P[0], P[1], P[2], P[3]};
  reinterpret_cast<float4*>(SQ + (size_t)chunk * DA_)[c4] = (float4){Q[0], Q[1], Q[2], Q[3]};
}

__global__ __launch_bounds__(256) void wkv_pass2(
    const float* __restrict__ td, float* __restrict__ SP, float* __restrict__ SQ)
{
  const int c4 = blockIdx.x * 256 + threadIdx.x;
  const float4 tdv = reinterpret_cast<const float4*>(td)[c4];
  float lamL[4] = {__expf(-__expf(tdv.x) * (float)CL), __expf(-__expf(tdv.y) * (float)CL),
                   __expf(-__expf(tdv.z) * (float)CL), __expf(-__expf(tdv.w) * (float)CL)};
  float P[4] = {0.f, 0.f, 0.f, 0.f}, Q[4] = {0.f, 0.f, 0.f, 0.f};
  for (int i = 0; i < NC; ++i) {
    float4* sp4 = reinterpret_cast<float4*>(SP + (size_t)i * DA_) + c4;
    float4* sq4 = reinterpret_cast<float4*>(SQ + (size_t)i * DA_) + c4;
    const float4 sp = *sp4, sq = *sq4;
    *sp4 = (float4){P[0], P[1], P[2], P[3]};   // exclusive prefix
    *sq4 = (float4){Q[0], Q[1], Q[2], Q[3]};
    P[0] = fmaf(lamL[0], P[0], sp.x); Q[0] = fmaf(lamL[0], Q[0], sq.x);
    P[1] = fmaf(lamL[1], P[1], sp.y); Q[1] = fmaf(lamL[1], Q[1], sq.y);
    P[2] = fmaf(lamL[2], P[2], sp.z); Q[2] = fmaf(lamL[2], Q[2], sq.z);
    P[3] = fmaf(lamL[3], P[3], sp.w); Q[3] = fmaf(lamL[3], Q[3], sq.w);
  }
}

__global__ __launch_bounds__(256) void wkv_pass3(
    const unsigned short* __restrict__ Kb, const unsigned short* __restrict__ Vb,
    const unsigned short* __restrict__ Rb, unsigned short* __restrict__ Ab,
    const float* __restrict__ td, const float* __restrict__ tf,
    const float* __restrict__ SP, const float* __restrict__ SQ)
{
  const int c4 = blockIdx.x * 256 + threadIdx.x;
  const int chunk = blockIdx.y;
  const int t0 = chunk * CL;
  const float4 tdv = reinterpret_cast<const float4*>(td)[c4];
  const float4 tfv = reinterpret_cast<const float4*>(tf)[c4];
  const float lam[4] = {__expf(-__expf(tdv.x)), __expf(-__expf(tdv.y)),
                        __expf(-__expf(tdv.z)), __expf(-__expf(tdv.w))};
  const float eu[4] = {__expf(tfv.x), __expf(tfv.y), __expf(tfv.z), __expf(tfv.w)};
  const float4 p0 = reinterpret_cast<const float4*>(SP + (size_t)chunk * DA_)[c4];
  const float4 q0 = reinterpret_cast<const float4*>(SQ + (size_t)chunk * DA_)[c4];
  float P[4] = {p0.x, p0.y, p0.z, p0.w};
  float Q[4] = {q0.x, q0.y, q0.z, q0.w};
  for (int t = t0; t < t0 + CL; ++t) {
    const ushort4 kq = reinterpret_cast<const ushort4*>(Kb + (size_t)t * DA_)[c4];
    const ushort4 vq = reinterpret_cast<const ushort4*>(Vb + (size_t)t * DA_)[c4];
    const ushort4 rq = reinterpret_cast<const ushort4*>(Rb + (size_t)t * DA_)[c4];
    const float kf[4] = {bf2f(kq.x), bf2f(kq.y), bf2f(kq.z), bf2f(kq.w)};
    const float vf[4] = {bf2f(vq.x), bf2f(vq.y), bf2f(vq.z), bf2f(vq.w)};
    const float rf[4] = {bf2f(rq.x), bf2f(rq.y), bf2f(rq.z), bf2f(rq.w)};
    ushort4 a;
    unsigned short* ap = (unsigned short*)&a;
#pragma unroll
    for (int j = 0; j < 4; ++j) {
      const float e = __expf(kf[j]);
      const float b = eu[j] * e;
      const float y = (P[j] + b * vf[j]) / (Q[j] + b);
      const float sr = 1.f / (1.f + __expf(-rf[j]));
      ap[j] = f2bf(sr * y);
      P[j] = fmaf(lam[j], P[j], e * vf[j]);
      Q[j] = fmaf(lam[j], Q[j], e);
    }
    reinterpret_cast<ushort4*>(Ab + (size_t)t * DA_)[c4] = a;
  }
}

// ---------------------------------------------------------------------------
extern "C" void kernel_launch(void* const* d_in, const int* in_sizes, int n_in,
                              void* d_out, int out_size, void* d_ws, size_t ws_size,
                              hipStream_t stream)
{
  const float* x   = (const float*)d_in[0];
  const float* tf  = (const float*)d_in[1];
  const float* td  = (const float*)d_in[2];
  const float* tmk = (const float*)d_in[3];
  const float* tmv = (const float*)d_in[4];
  const float* tmr = (const float*)d_in[5];
  const float* Wk  = (const float*)d_in[6];  // [NE, DA]
  const float* Wv  = (const float*)d_in[7];
  const float* Wr  = (const float*)d_in[8];
  const float* Wo  = (const float*)d_in[9];  // [DA, NE]
  float* out = (float*)d_out;

  const size_t MB = 1024 * 1024;
  char* ws = (char*)d_ws;

  const dim3 blk(256);
  const dim3 tblk(32, 8);
  const dim3 ggrid1(T_ / 128, DA_ / 128, 1);
  const size_t NEED_BATCH = 122 * MB;

  if (ws_size >= NEED_BATCH) {
    // ---- batched layout (121 MB) ----
    unsigned short* xmk = (unsigned short*)(ws + 0 * MB);    // 16 MB; reused as `a`
    unsigned short* xmv = (unsigned short*)(ws + 16 * MB);
    unsigned short* xmr = (unsigned short*)(ws + 32 * MB);
    unsigned short* WtK = (unsigned short*)(ws + 48 * MB);   // 8 MB; reused as WoT
    unsigned short* WtV = (unsigned short*)(ws + 56 * MB);
    unsigned short* WtR = (unsigned short*)(ws + 64 * MB);
    unsigned short* kb  = (unsigned short*)(ws + 72 * MB);   // 16 MB bf16
    unsigned short* vb  = (unsigned short*)(ws + 88 * MB);
    unsigned short* rb  = (unsigned short*)(ws + 104 * MB);
    float* sp = (float*)(ws + 120 * MB);                     // 512 KB
    float* sq = (float*)(ws + 120 * MB + 512 * 1024);

    transpose_cvt3<<<dim3(64, 64, 3), tblk, 0, stream>>>(Wk, Wv, Wr, WtK, WtV, WtR);
    mix3_cvt<<<TDA / 4 / 256, blk, 0, stream>>>(x, tmk, tmv, tmr, xmk, xmv, xmr);
    gemm3_bf16<<<dim3(T_ / 128, DA_ / 128, 3), blk, 0, stream>>>(
        xmk, xmv, xmr, WtK, WtV, WtR, kb, vb, rb, 1);

    wkv_pass1<<<dim3(DA_ / 4 / 256, NC), blk, 0, stream>>>(kb, vb, td, sp, sq);
    wkv_pass2<<<dim3(DA_ / 4 / 256), blk, 0, stream>>>(td, sp, sq);
    wkv_pass3<<<dim3(DA_ / 4 / 256, NC), blk, 0, stream>>>(kb, vb, rb, xmk, td, tf, sp, sq);

    transpose_cvt3<<<dim3(64, 64, 1), tblk, 0, stream>>>(Wo, Wo, Wo, WtK, WtK, WtK);
    gemm3_bf16<<<ggrid1, blk, 0, stream>>>(xmk, xmk, xmk, WtK, WtK, WtK, out, out, out, 0);
  } else {
    // ---- sequential fallback (105 MB) ----
    unsigned short* xmk = (unsigned short*)(ws + 0 * MB);
    unsigned short* xmv = (unsigned short*)(ws + 16 * MB);
    unsigned short* xmr = (unsigned short*)(ws + 32 * MB);
    unsigned short* Wt  = (unsigned short*)(ws + 48 * MB);   // single, reused 4x
    unsigned short* kb  = (unsigned short*)(ws + 56 * MB);
    unsigned short* vb  = (unsigned short*)(ws + 72 * MB);
    unsigned short* rb  = (unsigned short*)(ws + 88 * MB);
    float* sp = (float*)(ws + 104 * MB);
    float* sq = (float*)(ws + 104 * MB + 512 * 1024);

    mix3_cvt<<<TDA / 4 / 256, blk, 0, stream>>>(x, tmk, tmv, tmr, xmk, xmv, xmr);
    transpose_cvt3<<<dim3(64, 64, 1), tblk, 0, stream>>>(Wk, Wk, Wk, Wt, Wt, Wt);
    gemm3_bf16<<<ggrid1, blk, 0, stream>>>(xmk, xmk, xmk, Wt, Wt, Wt, kb, kb, kb, 1);
    transpose_cvt3<<<dim3(64, 64, 1), tblk, 0, stream>>>(Wv, Wv, Wv, Wt, Wt, Wt);
    gemm3_bf16<<<ggrid1, blk, 0, stream>>>(xmv, xmv, xmv, Wt, Wt, Wt, vb, vb, vb, 1);
    transpose_cvt3<<<dim3(64, 64, 1), tblk, 0, stream>>>(Wr, Wr, Wr, Wt, Wt, Wt);
    gemm3_bf16<<<ggrid1, blk, 0, stream>>>(xmr, xmr, xmr, Wt, Wt, Wt, rb, rb, rb, 1);

    wkv_pass1<<<dim3(DA_ / 4 / 256, NC), blk, 0, stream>>>(kb, vb, td, sp, sq);
    wkv_pass2<<<dim3(DA_ / 4 / 256), blk, 0, stream>>>(td, sp, sq);
    wkv_pass3<<<dim3(DA_ / 4 / 256, NC), blk, 0, stream>>>(kb, vb, rb, xmk, td, tf, sp, sq);

    transpose_cvt3<<<dim3(64, 64, 1), tblk, 0, stream>>>(Wo, Wo, Wo, Wt, Wt, Wt);
    gemm3_bf16<<<ggrid1, blk, 0, stream>>>(xmk, xmk, xmk, Wt, Wt, Wt, out, out, out, 0);
  }
}

// Round 6
// 350.017 us; speedup vs baseline: 5.4816x; 1.2032x over previous
//
#include <hip/hip_runtime.h>
#include <math.h>

#define T_ 4096
#define NE_ 2048
#define DA_ 2048
#define TDA ((size_t)T_ * NE_)

constexpr int NC = 128;       // time chunks for the WKV scan
constexpr int CL = T_ / NC;   // 32 steps per chunk

typedef __attribute__((ext_vector_type(8))) short short8;
typedef __attribute__((ext_vector_type(4))) float f32x4;

__device__ __forceinline__ unsigned short f2bf(float f) {
  union { float f; unsigned int u; } v; v.f = f;
  unsigned int u = v.u;
  return (unsigned short)((u + 0x7FFFu + ((u >> 16) & 1u)) >> 16);  // RNE
}
__device__ __forceinline__ float bf2f(unsigned short h) {
  union { unsigned int u; float f; } v; v.u = ((unsigned int)h) << 16;
  return v.f;
}

__device__ __forceinline__ void gload_lds16(const void* g, void* l) {
  __builtin_amdgcn_global_load_lds(
      (const __attribute__((address_space(1))) void*)g,
      (__attribute__((address_space(3))) void*)l, 16, 0, 0);
}

// ---------------------------------------------------------------------------
// bf16 MFMA GEMM core, BK=64 (2 MFMA K-slices per barrier pair):
//   C[4096][2048] = A[4096][2048] * Bt[2048][2048]^T      (K = 2048)
// 128x128 tile, 4 waves (2x2), 4x4 x (16x16x32 MFMA) x 2 slices per K-step.
// LDS [128][64] bf16 per matrix (32 KB total). Row = 128B = 32 banks, so the
// 8 16B-chunks of each row are XOR-swizzled: phys = logical ^ (row & 7).
// Achieved rule-21 style: linear gload_lds dest + pre-swizzled global source
// chunk + the same XOR on ds_read addresses. Per-16-lane b128 phase each of
// the 8 chunk slots is hit exactly twice -> 2-way, free (m136).
// ---------------------------------------------------------------------------
__device__ __forceinline__ void gemm_core(
    const unsigned short* __restrict__ A, const unsigned short* __restrict__ Bt,
    void* __restrict__ C, int c_bf16)
{
  constexpr int K = 2048, N = 2048;
  __shared__ unsigned short As[128 * 64];
  __shared__ unsigned short Bs[128 * 64];

  const int tid = threadIdx.x;
  const int w = tid >> 6, lane = tid & 63;
  const int bm = blockIdx.x * 128, bn = blockIdx.y * 128;
  const int wr = w >> 1, wc = w & 1;

  f32x4 acc[4][4];
#pragma unroll
  for (int m = 0; m < 4; ++m)
#pragma unroll
    for (int n = 0; n < 4; ++n) acc[m][n] = (f32x4){0.f, 0.f, 0.f, 0.f};

  // staging: wave w covers tile rows [w*32, w*32+32): 4 gloads of 8 rows each.
  // lane -> row (lane>>3), source chunk (lane&7) ^ (lane>>3)  (involution).
  const int sr8 = lane >> 3;
  const int gcs = (lane & 7) ^ sr8;
  const size_t gA0 = (size_t)(bm + w * 32 + sr8) * K + gcs * 8;
  const size_t gB0 = (size_t)(bn + w * 32 + sr8) * K + gcs * 8;
  unsigned short* lA = &As[(w * 32) * 64];   // wave-uniform; HW adds lane*16B
  unsigned short* lB = &Bs[(w * 32) * 64];

  const int lr = lane & 15, ck = lane >> 4;
  const int x7 = lr & 7;
  const int arow = wr * 64 + lr;
  const int brow = wc * 64 + lr;

  for (int kk = 0; kk < K; kk += 64) {
    __syncthreads();                        // previous tile consumed
#pragma unroll
    for (int g = 0; g < 4; ++g) {
      gload_lds16(A + gA0 + kk + (size_t)(g * 8) * K, lA + g * 512);
      gload_lds16(Bt + gB0 + kk + (size_t)(g * 8) * K, lB + g * 512);
    }
    __syncthreads();                        // drains vmcnt -> LDS ready

#pragma unroll
    for (int s = 0; s < 2; ++s) {
      const int c0 = ((s * 4 + ck) ^ x7) * 8;   // swizzled elem offset in row
      short8 af[4], bfr[4];
#pragma unroll
      for (int m = 0; m < 4; ++m)
        af[m] = *reinterpret_cast<const short8*>(&As[(arow + m * 16) * 64 + c0]);
#pragma unroll
      for (int n = 0; n < 4; ++n)
        bfr[n] = *reinterpret_cast<const short8*>(&Bs[(brow + n * 16) * 64 + c0]);
#pragma unroll
      for (int m = 0; m < 4; ++m)
#pragma unroll
        for (int n = 0; n < 4; ++n)
          acc[m][n] = __builtin_amdgcn_mfma_f32_16x16x32_bf16(af[m], bfr[n], acc[m][n], 0, 0, 0);
    }
  }

  // C/D layout (verified m89/m91): col = lane&15, row = (lane>>4)*4 + reg
  const int crow0 = bm + wr * 64 + (lane >> 4) * 4;
  const int ccol0 = bn + wc * 64 + (lane & 15);
  if (c_bf16) {
    unsigned short* Cb = (unsigned short*)C;
#pragma unroll
    for (int m = 0; m < 4; ++m)
#pragma unroll
      for (int n = 0; n < 4; ++n)
#pragma unroll
        for (int j = 0; j < 4; ++j)
          Cb[(size_t)(crow0 + m * 16 + j) * N + ccol0 + n * 16] = f2bf(acc[m][n][j]);
  } else {
    float* Cf = (float*)C;
#pragma unroll
    for (int m = 0; m < 4; ++m)
#pragma unroll
      for (int n = 0; n < 4; ++n)
#pragma unroll
        for (int j = 0; j < 4; ++j)
          Cf[(size_t)(crow0 + m * 16 + j) * N + ccol0 + n * 16] = acc[m][n][j];
  }
}

// z-batched GEMM: blockIdx.z selects (A, Bt, C) triple.
__global__ __launch_bounds__(256) void gemm3_bf16(
    const unsigned short* __restrict__ A0, const unsigned short* __restrict__ A1,
    const unsigned short* __restrict__ A2,
    const unsigned short* __restrict__ B0, const unsigned short* __restrict__ B1,
    const unsigned short* __restrict__ B2,
    void* __restrict__ C0, void* __restrict__ C1, void* __restrict__ C2,
    int c_bf16)
{
  const int z = blockIdx.z;
  const unsigned short* A = (z == 0) ? A0 : (z == 1) ? A1 : A2;
  const unsigned short* B = (z == 0) ? B0 : (z == 1) ? B1 : B2;
  void* C = (z == 0) ? C0 : (z == 1) ? C1 : C2;
  gemm_core(A, B, C, c_bf16);
}

// ---------------------------------------------------------------------------
// z-batched transpose + fp32->bf16 for 2048x2048: O[n][k] = bf16(W[k][n])
// ---------------------------------------------------------------------------
__global__ __launch_bounds__(256) void transpose_cvt3(
    const float* __restrict__ W0, const float* __restrict__ W1,
    const float* __restrict__ W2,
    unsigned short* __restrict__ O0, unsigned short* __restrict__ O1,
    unsigned short* __restrict__ O2)
{
  constexpr int K = 2048, N = 2048;
  const int z = blockIdx.z;
  const float* W = (z == 0) ? W0 : (z == 1) ? W1 : W2;
  unsigned short* O = (z == 0) ? O0 : (z == 1) ? O1 : O2;

  __shared__ float tile[32][33];
  const int bk = blockIdx.y * 32;
  const int bn = blockIdx.x * 32;
  const int tx = threadIdx.x;   // 0..31
  const int ty = threadIdx.y;   // 0..7
#pragma unroll
  for (int i = 0; i < 32; i += 8)
    tile[ty + i][tx] = W[(size_t)(bk + ty + i) * N + bn + tx];
  __syncthreads();
#pragma unroll
  for (int i = 0; i < 32; i += 8)
    O[(size_t)(bn + ty + i) * K + bk + tx] = f2bf(tile[tx][ty + i]);
}

// ---------------------------------------------------------------------------
// Fused triple time-mix + fp32->bf16 (reads x once)
// ---------------------------------------------------------------------------
__global__ __launch_bounds__(256) void mix3_cvt(
    const float* __restrict__ x,
    const float* __restrict__ tmk, const float* __restrict__ tmv,
    const float* __restrict__ tmr,
    unsigned short* __restrict__ ok, unsigned short* __restrict__ ov,
    unsigned short* __restrict__ orr)
{
  const int i = blockIdx.x * 256 + threadIdx.x;   // float4 index
  const int t = i / (NE_ / 4);
  const int e4 = i % (NE_ / 4);
  const float4 xc = reinterpret_cast<const float4*>(x)[i];
  float4 xp = make_float4(0.f, 0.f, 0.f, 0.f);
  if (t > 0) xp = reinterpret_cast<const float4*>(x)[i - NE_ / 4];
  const float4 dx = make_float4(xc.x - xp.x, xc.y - xp.y, xc.z - xp.z, xc.w - xp.w);

  float4 m;
  ushort4 r;
  m = reinterpret_cast<const float4*>(tmk)[e4];
  r.x = f2bf(xp.x + m.x * dx.x); r.y = f2bf(xp.y + m.y * dx.y);
  r.z = f2bf(xp.z + m.z * dx.z); r.w = f2bf(xp.w + m.w * dx.w);
  reinterpret_cast<ushort4*>(ok)[i] = r;
  m = reinterpret_cast<const float4*>(tmv)[e4];
  r.x = f2bf(xp.x + m.x * dx.x); r.y = f2bf(xp.y + m.y * dx.y);
  r.z = f2bf(xp.z + m.z * dx.z); r.w = f2bf(xp.w + m.w * dx.w);
  reinterpret_cast<ushort4*>(ov)[i] = r;
  m = reinterpret_cast<const float4*>(tmr)[e4];
  r.x = f2bf(xp.x + m.x * dx.x); r.y = f2bf(xp.y + m.y * dx.y);
  r.z = f2bf(xp.z + m.z * dx.z); r.w = f2bf(xp.w + m.w * dx.w);
  reinterpret_cast<ushort4*>(orr)[i] = r;
}

// ---------------------------------------------------------------------------
// WKV chunked linear scan, bf16 k/v, 4 channels per thread.
//   P_t = lam*P + e^{k_t} v_t ,  Q_t = lam*Q + e^{k_t}
//   y_t = (P_{t-1} + e^{u+k_t} v_t) / (Q_{t-1} + e^{u+k_t})
// 1-wave blocks, grid (DA/256, NC) = (8, 128) = 1024 blocks for latency hiding.
// ---------------------------------------------------------------------------
__global__ __launch_bounds__(64) void wkv_pass1(
    const unsigned short* __restrict__ Kb, const unsigned short* __restrict__ Vb,
    const float* __restrict__ td, float* __restrict__ SP, float* __restrict__ SQ)
{
  const int c4 = blockIdx.x * 64 + threadIdx.x;   // 4-channel group
  const int chunk = blockIdx.y;
  const int t0 = chunk * CL;
  const float4 tdv = reinterpret_cast<const float4*>(td)[c4];
  float lam[4] = {__expf(-__expf(tdv.x)), __expf(-__expf(tdv.y)),
                  __expf(-__expf(tdv.z)), __expf(-__expf(tdv.w))};
  float P[4] = {0.f, 0.f, 0.f, 0.f}, Q[4] = {0.f, 0.f, 0.f, 0.f};
#pragma unroll 4
  for (int t = t0; t < t0 + CL; ++t) {
    const ushort4 kq = reinterpret_cast<const ushort4*>(Kb + (size_t)t * DA_)[c4];
    const ushort4 vq = reinterpret_cast<const ushort4*>(Vb + (size_t)t * DA_)[c4];
    const float kf[4] = {bf2f(kq.x), bf2f(kq.y), bf2f(kq.z), bf2f(kq.w)};
    const float vf[4] = {bf2f(vq.x), bf2f(vq.y), bf2f(vq.z), bf2f(vq.w)};
#pragma unroll
    for (int j = 0; j < 4; ++j) {
      const float e = __expf(kf[j]);
      P[j] = fmaf(lam[j], P[j], e * vf[j]);
      Q[j] = fmaf(lam[j], Q[j], e);
    }
  }
  reinterpret_cast<float4*>(SP + (size_t)chunk * DA_)[c4] = (float4){P[0], P[1], P[2], P[3]};
  reinterpret_cast<float4*>(SQ + (size_t)chunk * DA_)[c4] = (float4){Q[0], Q[1], Q[2], Q[3]};
}

// per-channel exclusive scan over NC chunk-sums; tiles of 16 independent loads
__global__ __launch_bounds__(256) void wkv_pass2(
    const float* __restrict__ td, float* __restrict__ SP, float* __restrict__ SQ)
{
  const int c = blockIdx.x * 256 + threadIdx.x;   // one channel per thread
  const float lamL = __expf(-__expf(td[c]) * (float)CL);  // lam^CL
  float P = 0.f, Q = 0.f;
  for (int i0 = 0; i0 < NC; i0 += 16) {
    float sp[16], sq[16];
#pragma unroll
    for (int j = 0; j < 16; ++j) {
      sp[j] = SP[(size_t)(i0 + j) * DA_ + c];
      sq[j] = SQ[(size_t)(i0 + j) * DA_ + c];
    }
#pragma unroll
    for (int j = 0; j < 16; ++j) {
      SP[(size_t)(i0 + j) * DA_ + c] = P;   // exclusive prefix
      SQ[(size_t)(i0 + j) * DA_ + c] = Q;
      P = fmaf(lamL, P, sp[j]);
      Q = fmaf(lamL, Q, sq[j]);
    }
  }
}

__global__ __launch_bounds__(64) void wkv_pass3(
    const unsigned short* __restrict__ Kb, const unsigned short* __restrict__ Vb,
    const unsigned short* __restrict__ Rb, unsigned short* __restrict__ Ab,
    const float* __restrict__ td, const float* __restrict__ tf,
    const float* __restrict__ SP, const float* __restrict__ SQ)
{
  const int c4 = blockIdx.x * 64 + threadIdx.x;
  const int chunk = blockIdx.y;
  const int t0 = chunk * CL;
  const float4 tdv = reinterpret_cast<const float4*>(td)[c4];
  const float4 tfv = reinterpret_cast<const float4*>(tf)[c4];
  const float lam[4] = {__expf(-__expf(tdv.x)), __expf(-__expf(tdv.y)),
                        __expf(-__expf(tdv.z)), __expf(-__expf(tdv.w))};
  const float eu[4] = {__expf(tfv.x), __expf(tfv.y), __expf(tfv.z), __expf(tfv.w)};
  const float4 p0 = reinterpret_cast<const float4*>(SP + (size_t)chunk * DA_)[c4];
  const float4 q0 = reinterpret_cast<const float4*>(SQ + (size_t)chunk * DA_)[c4];
  float P[4] = {p0.x, p0.y, p0.z, p0.w};
  float Q[4] = {q0.x, q0.y, q0.z, q0.w};
#pragma unroll 4
  for (int t = t0; t < t0 + CL; ++t) {
    const ushort4 kq = reinterpret_cast<const ushort4*>(Kb + (size_t)t * DA_)[c4];
    const ushort4 vq = reinterpret_cast<const ushort4*>(Vb + (size_t)t * DA_)[c4];
    const ushort4 rq = reinterpret_cast<const ushort4*>(Rb + (size_t)t * DA_)[c4];
    const float kf[4] = {bf2f(kq.x), bf2f(kq.y), bf2f(kq.z), bf2f(kq.w)};
    const float vf[4] = {bf2f(vq.x), bf2f(vq.y), bf2f(vq.z), bf2f(vq.w)};
    const float rf[4] = {bf2f(rq.x), bf2f(rq.y), bf2f(rq.z), bf2f(rq.w)};
    ushort4 a;
    unsigned short* ap = (unsigned short*)&a;
#pragma unroll
    for (int j = 0; j < 4; ++j) {
      const float e = __expf(kf[j]);
      const float b = eu[j] * e;
      const float y = (P[j] + b * vf[j]) / (Q[j] + b);
      const float sr = 1.f / (1.f + __expf(-rf[j]));
      ap[j] = f2bf(sr * y);
      P[j] = fmaf(lam[j], P[j], e * vf[j]);
      Q[j] = fmaf(lam[j], Q[j], e);
    }
    reinterpret_cast<ushort4*>(Ab + (size_t)t * DA_)[c4] = a;
  }
}

// ---------------------------------------------------------------------------
extern "C" void kernel_launch(void* const* d_in, const int* in_sizes, int n_in,
                              void* d_out, int out_size, void* d_ws, size_t ws_size,
                              hipStream_t stream)
{
  const float* x   = (const float*)d_in[0];
  const float* tf  = (const float*)d_in[1];
  const float* td  = (const float*)d_in[2];
  const float* tmk = (const float*)d_in[3];
  const float* tmv = (const float*)d_in[4];
  const float* tmr = (const float*)d_in[5];
  const float* Wk  = (const float*)d_in[6];  // [NE, DA]
  const float* Wv  = (const float*)d_in[7];
  const float* Wr  = (const float*)d_in[8];
  const float* Wo  = (const float*)d_in[9];  // [DA, NE]
  float* out = (float*)d_out;

  const size_t MB = 1024 * 1024;
  char* ws = (char*)d_ws;

  const dim3 blk(256);
  const dim3 wblk(64);
  const dim3 tblk(32, 8);
  const dim3 ggrid1(T_ / 128, DA_ / 128, 1);
  const dim3 wgrid(DA_ / 4 / 64, NC);         // (8, 128)
  const size_t NEED_BATCH = 122 * MB;

  if (ws_size >= NEED_BATCH) {
    // ---- batched layout (122 MB) ----
    unsigned short* xmk = (unsigned short*)(ws + 0 * MB);    // 16 MB; reused as `a`
    unsigned short* xmv = (unsigned short*)(ws + 16 * MB);
    unsigned short* xmr = (unsigned short*)(ws + 32 * MB);
    unsigned short* WtK = (unsigned short*)(ws + 48 * MB);   // 8 MB; reused as WoT
    unsigned short* WtV = (unsigned short*)(ws + 56 * MB);
    unsigned short* WtR = (unsigned short*)(ws + 64 * MB);
    unsigned short* kb  = (unsigned short*)(ws + 72 * MB);   // 16 MB bf16
    unsigned short* vb  = (unsigned short*)(ws + 88 * MB);
    unsigned short* rb  = (unsigned short*)(ws + 104 * MB);
    float* sp = (float*)(ws + 120 * MB);                     // 1 MB each (NC=128)
    float* sq = (float*)(ws + 121 * MB);

    transpose_cvt3<<<dim3(64, 64, 3), tblk, 0, stream>>>(Wk, Wv, Wr, WtK, WtV, WtR);
    mix3_cvt<<<TDA / 4 / 256, blk, 0, stream>>>(x, tmk, tmv, tmr, xmk, xmv, xmr);
    gemm3_bf16<<<dim3(T_ / 128, DA_ / 128, 3), blk, 0, stream>>>(
        xmk, xmv, xmr, WtK, WtV, WtR, kb, vb, rb, 1);

    // Wo transpose moved up: WtK is dead after gemm3
    transpose_cvt3<<<dim3(64, 64, 1), tblk, 0, stream>>>(Wo, Wo, Wo, WtK, WtK, WtK);

    wkv_pass1<<<wgrid, wblk, 0, stream>>>(kb, vb, td, sp, sq);
    wkv_pass2<<<dim3(DA_ / 256), blk, 0, stream>>>(td, sp, sq);
    wkv_pass3<<<wgrid, wblk, 0, stream>>>(kb, vb, rb, xmk, td, tf, sp, sq);

    gemm3_bf16<<<ggrid1, blk, 0, stream>>>(xmk, xmk, xmk, WtK, WtK, WtK, out, out, out, 0);
  } else {
    // ---- sequential fallback (107 MB) ----
    unsigned short* xmk = (unsigned short*)(ws + 0 * MB);
    unsigned short* xmv = (unsigned short*)(ws + 16 * MB);
    unsigned short* xmr = (unsigned short*)(ws + 32 * MB);
    unsigned short* Wt  = (unsigned short*)(ws + 48 * MB);   // single, reused 4x
    unsigned short* kb  = (unsigned short*)(ws + 56 * MB);
    unsigned short* vb  = (unsigned short*)(ws + 72 * MB);
    unsigned short* rb  = (unsigned short*)(ws + 88 * MB);
    float* sp = (float*)(ws + 104 * MB);
    float* sq = (float*)(ws + 105 * MB);

    mix3_cvt<<<TDA / 4 / 256, blk, 0, stream>>>(x, tmk, tmv, tmr, xmk, xmv, xmr);
    transpose_cvt3<<<dim3(64, 64, 1), tblk, 0, stream>>>(Wk, Wk, Wk, Wt, Wt, Wt);
    gemm3_bf16<<<ggrid1, blk, 0, stream>>>(xmk, xmk, xmk, Wt, Wt, Wt, kb, kb, kb, 1);
    transpose_cvt3<<<dim3(64, 64, 1), tblk, 0, stream>>>(Wv, Wv, Wv, Wt, Wt, Wt);
    gemm3_bf16<<<ggrid1, blk, 0, stream>>>(xmv, xmv, xmv, Wt, Wt, Wt, vb, vb, vb, 1);
    transpose_cvt3<<<dim3(64, 64, 1), tblk, 0, stream>>>(Wr, Wr, Wr, Wt, Wt, Wt);
    gemm3_bf16<<<ggrid1, blk, 0, stream>>>(xmr, xmr, xmr, Wt, Wt, Wt, rb, rb, rb, 1);

    wkv_pass1<<<wgrid, wblk, 0, stream>>>(kb, vb, td, sp, sq);
    wkv_pass2<<<dim3(DA_ / 256), blk, 0, stream>>>(td, sp, sq);
    wkv_pass3<<<wgrid, wblk, 0, stream>>>(kb, vb, rb, xmk, td, tf, sp, sq);

    transpose_cvt3<<<dim3(64, 64, 1), tblk, 0, stream>>>(Wo, Wo, Wo, Wt, Wt, Wt);
    gemm3_bf16<<<ggrid1, blk, 0, stream>>>(xmk, xmk, xmk, Wt, Wt, Wt, out, out, out, 0);
  }
}